// Round 11
// baseline (387.744 us; speedup 1.0000x reference)
//
#include <hip/hip_runtime.h>
#include <math.h>

#define N_NODES 50000
#define E_EDGES 400000
#define NPRE_BLOCKS 6250          // N_NODES/8
#define NHIST_BLOCKS 1563         // ceil(E/256)
#define NEDGE_BLOCKS 6250         // E_EDGES/64
#define NSCAN_BLOCKS 50

typedef _Float16 f16x2 __attribute__((ext_vector_type(2)));
typedef _Float16 f16x4 __attribute__((ext_vector_type(4)));
typedef _Float16 f16x8 __attribute__((ext_vector_type(8)));
typedef float    f32x4 __attribute__((ext_vector_type(4)));

static constexpr float S_IN      = 0.17677669529663687f;   // 1/sqrt(32)
static constexpr float S_MID     = 0.125f;                 // 1/sqrt(64)
static constexpr float S_SE      = 0.08838834764831843f;   // 1/sqrt(128)
static constexpr float INV_NN    = 0.35355339059327373f;   // 1/sqrt(8)
static constexpr float INV_SQRT3 = 0.5773502691896258f;
static constexpr float FC1_S     = 0.25f;                  // 1/sqrt(16)
static constexpr float FC2_S     = 0.125f;                 // 1/sqrt(64)

// Wave-local LDS ordering (one instruction stream per wave -> lgkmcnt(0)
// orders this wave's ds_write -> ds_read). No s_barrier.
#define WAVE_LDS_FENCE() asm volatile("s_waitcnt lgkmcnt(0)" ::: "memory")

// 64-lane sum via DPP: row_shr 1/2/4/8, bcast15, bcast31.
__device__ inline float wave_reduce_dpp(float v) {
    int x;
    x = __builtin_amdgcn_update_dpp(0, __float_as_int(v), 0x111, 0xf, 0xf, true); v += __int_as_float(x);
    x = __builtin_amdgcn_update_dpp(0, __float_as_int(v), 0x112, 0xf, 0xf, true); v += __int_as_float(x);
    x = __builtin_amdgcn_update_dpp(0, __float_as_int(v), 0x114, 0xf, 0xf, true); v += __int_as_float(x);
    x = __builtin_amdgcn_update_dpp(0, __float_as_int(v), 0x118, 0xf, 0xf, true); v += __int_as_float(x);
    x = __builtin_amdgcn_update_dpp(0, __float_as_int(v), 0x142, 0xa, 0xf, true); v += __int_as_float(x);
    x = __builtin_amdgcn_update_dpp(0, __float_as_int(v), 0x143, 0xc, 0xf, true); v += __int_as_float(x);
    return __int_as_float(__builtin_amdgcn_readlane(__float_as_int(v), 63));
}

// Global spin-barrier (co-resident 50-block kernel; correctness-proven r6/r8/r10).
__device__ inline void gsync(int* cnt, int target) {
    __syncthreads();
    if (threadIdx.x == 0) {
        __hip_atomic_fetch_add(cnt, 1, __ATOMIC_ACQ_REL, __HIP_MEMORY_SCOPE_AGENT);
        while (__hip_atomic_load(cnt, __ATOMIC_ACQUIRE, __HIP_MEMORY_SCOPE_AGENT) < target)
            __builtin_amdgcn_s_sleep(8);
    }
    __syncthreads();
    __threadfence();
}

// ---------------------------------------------------------------------------
// Kernel A (fused): blocks [0,NPRE) per-node precompute (both sc+lin1 paths,
// r9 form) + zero its nacc rows; rest: dst histogram ONLY (ES convert
// removed — edge reads edge_scalars directly). Block 0 zeroes sync_cnt.
// ---------------------------------------------------------------------------
__global__ __launch_bounds__(256) void pre_hist_kernel(
    const float* __restrict__ node_input, const float* __restrict__ node_attr,
    const float* __restrict__ w_sc0, const float* __restrict__ w_sc1,
    const float* __restrict__ w_lin1_0, const float* __restrict__ w_lin1_1,
    float* __restrict__ out_self, _Float16* __restrict__ ws_h,
    const int* __restrict__ edge_dst, int* __restrict__ counts,
    float* __restrict__ nacc, int* __restrict__ sync_cnt)
{
    const int t = threadIdx.x;
    if (blockIdx.x == 0 && t == 0) *sync_cnt = 0;
    if (blockIdx.x >= NPRE_BLOCKS) {          // histogram role (now near-free)
        const int e = (blockIdx.x - NPRE_BLOCKS) * 256 + t;
        if (e < E_EDGES) atomicAdd(&counts[edge_dst[e]], 1);
        return;
    }
    const int n0 = blockIdx.x * 8;
    __shared__ __align__(16) float sx[8 * 128];   // [k][ x0(32) | m*32+u (96) ]
    __shared__ float sa[8];
    {   // staged transpose: x0 straight, x1 scattered to [m][u]
        const int k = t >> 5, q = t & 31;
        const float4 v = ((const float4*)(node_input + (size_t)n0 * 128))[t];
        if (q < 8) {
            *(float4*)&sx[k * 128 + q * 4] = v;
        } else {
            const int base = q * 4 - 32;          // x1 element index u*3+m
            const float vv[4] = {v.x, v.y, v.z, v.w};
            #pragma unroll
            for (int j = 0; j < 4; ++j) {
                const int uj = (base + j) / 3, mj = (base + j) % 3;
                sx[k * 128 + 32 + mj * 32 + uj] = vv[j];
            }
        }
    }
    {   // zero this block's nacc rows
        float4* nz = (float4*)(nacc + (size_t)n0 * 256);
        const float4 z4 = {0.f, 0.f, 0.f, 0.f};
        nz[t] = z4; nz[t + 256] = z4;
    }
    if (t < 8) sa[t] = node_attr[n0 + t];
    __syncthreads();

    const int half = t >> 7;
    const int idx  = t & 127;
    float wcol[32];
    int xoff = 0;
    if (idx < 32) {
        const float* __restrict__ W = half ? w_lin1_0 : w_sc0;
        #pragma unroll
        for (int u = 0; u < 32; ++u) wcol[u] = W[u * 32 + idx];
    } else {
        const float* __restrict__ W = half ? w_lin1_1 : w_sc1;
        const int j = idx - 32;
        const int w = j / 3; const int m = j % 3;
        xoff = 32 + m * 32;
        #pragma unroll
        for (int u = 0; u < 32; ++u) wcol[u] = W[u * 32 + w];
    }
    #pragma unroll
    for (int k = 0; k < 8; ++k) {
        const float* xb = sx + k * 128 + xoff;
        float acc = 0.f;
        #pragma unroll
        for (int u4 = 0; u4 < 8; ++u4) {          // broadcast f32x4 reads
            const f32x4 xv = *(const f32x4*)&xb[u4 * 4];
            acc += xv[0] * wcol[u4 * 4 + 0];
            acc += xv[1] * wcol[u4 * 4 + 1];
            acc += xv[2] * wcol[u4 * 4 + 2];
            acc += xv[3] * wcol[u4 * 4 + 3];
        }
        const float v = acc * sa[k] * S_IN;
        if (half) ws_h[(size_t)(n0 + k) * 128 + idx] = (_Float16)v;
        else      out_self[(size_t)(n0 + k) * 128 + idx] = v;
    }
}

// ---------------------------------------------------------------------------
// Fused scan+fixup: 50 blocks x 1024, ONE spin barrier. Blocks 0..48 scan
// their 1024-node chunk; block 49 does the one-time weight prep; after the
// barrier blocks 0..48 add the cross-block prefix and write cursor.
// ---------------------------------------------------------------------------
__global__ __launch_bounds__(1024) void scan_fused_kernel(
    const int* __restrict__ counts, int* __restrict__ cursor,
    int* __restrict__ bsum, int* __restrict__ sync_cnt,
    const float* __restrict__ fc_w1, const float* __restrict__ fc_w2,
    const float* __restrict__ w_se0a, const float* __restrict__ w_se0b,
    const float* __restrict__ w_se1a, const float* __restrict__ w_se1b,
    _Float16* __restrict__ W2T_g, _Float16* __restrict__ W1T_g,
    _Float16* __restrict__ BT_g)
{
    const int t = threadIdx.x, b = blockIdx.x;
    const int idx = b * 1024 + t;
    __shared__ int swv[16], sex[16];
    __shared__ int boff_s;
    int myexc = 0;

    if (b < 49) {
        const int c = (idx < N_NODES) ? counts[idx] : 0;
        int v = c, x;
        x = __builtin_amdgcn_update_dpp(0, v, 0x111, 0xf, 0xf, true); v += x;
        x = __builtin_amdgcn_update_dpp(0, v, 0x112, 0xf, 0xf, true); v += x;
        x = __builtin_amdgcn_update_dpp(0, v, 0x114, 0xf, 0xf, true); v += x;
        x = __builtin_amdgcn_update_dpp(0, v, 0x118, 0xf, 0xf, true); v += x;
        x = __builtin_amdgcn_update_dpp(0, v, 0x142, 0xa, 0xf, true); v += x;
        x = __builtin_amdgcn_update_dpp(0, v, 0x143, 0xc, 0xf, true); v += x;
        const int wid = t >> 6;
        if ((t & 63) == 63) swv[wid] = v;
        __syncthreads();
        if (t < 16) {
            int a = 0;
            for (int j = 0; j < t; ++j) a += swv[j];
            sex[t] = a;
            if (t == 15) bsum[b] = a + swv[15];
        }
        __syncthreads();
        myexc = v - c + sex[wid];                 // block-local exclusive
    } else {                                      // b == 49: weight prep
        for (int u = t; u < 8192; u += 1024) {
            const int k = u >> 7, c = u & 127;
            W2T_g[c * 72 + k] = (_Float16)fc_w2[u];
        }
        {                                          // pad k=64..71
            W2T_g[(t >> 3) * 72 + 64 + (t & 7)] = (_Float16)0.f;
        }
        {                                          // W1T[j][k], k<16
            const int j = t >> 4, k = t & 15;
            W1T_g[t] = (_Float16)fc_w1[k * 64 + j];
        }
        for (int u = t; u < 2112; u += 1024) BT_g[u] = (_Float16)0.f;
        __syncthreads();
        if (t < 256) {   // col 2p: {se0a|se1b} on comp p; col 2p+1: {se1a|se0b}
            const int uu = t & 63, p = t >> 6;
            const float ev = (p == 0) ? w_se0a[uu] : w_se1b[uu];
            const float ov = (p == 0) ? w_se1a[uu] : w_se0b[uu];
            BT_g[(2 * p) * 264 + 4 * uu + p]     = (_Float16)ev;
            BT_g[(2 * p + 1) * 264 + 4 * uu + p] = (_Float16)ov;
        }
    }
    gsync(sync_cnt, NSCAN_BLOCKS);

    if (b < 49) {
        if (t < 64) {
            int vv = (t < b) ? bsum[t] : 0;        // b <= 48 < 64
            #pragma unroll
            for (int off = 32; off >= 1; off >>= 1) vv += __shfl_down(vv, off, 64);
            if (t == 0) boff_s = vv;
        }
        __syncthreads();
        if (idx < N_NODES) cursor[idx] = myexc + boff_s;
    }
}

__global__ __launch_bounds__(256) void scatter_kernel(
    const int* __restrict__ edge_dst, int* __restrict__ cursor,
    int* __restrict__ sorted_eid)
{
    const int e = blockIdx.x * 256 + threadIdx.x;
    if (e < E_EDGES) {
        const int p = atomicAdd(&cursor[edge_dst[e]], 1);
        sorted_eid[p] = e;
    }
}

// ---------------------------------------------------------------------------
// Kernel B: per-edge, dst-sorted, 64 edges/block, 4 waves, BARRIER-FREE.
// r9 structure (125us verified) with ONE change: b_es loads edge_scalars
// f32 directly (2x f32x4, convert in-reg — same rounding as the old ES_h
// precompute => bitwise-identical h). Removes the ES_h pipeline stage.
// (256,4) — r6/r8 proved tighter bounds spill the unified VGPR+AGPR file.
// ---------------------------------------------------------------------------
__global__ __launch_bounds__(256, 4) void edge_kernel(
    const _Float16* __restrict__ ws_h,
    const int* __restrict__ edge_src, const int* __restrict__ edge_dst,
    const float* __restrict__ edge_attr, const float* __restrict__ edge_scalars,
    const _Float16* __restrict__ W2T_g, const _Float16* __restrict__ W1T_g,
    const _Float16* __restrict__ BT_g,
    const int* __restrict__ sorted_eid,
    float* __restrict__ nacc, float* __restrict__ edge_out)
{
    __shared__ __align__(16) _Float16 sArena[17536];
    __shared__ __align__(16) float sEA[64 * 4];
    __shared__ __align__(16) float sDep[4][36];
    __shared__ int sSRC[64];
    __shared__ int sDST[64];
    __shared__ int sEID[64];

    _Float16* __restrict__ sHT   = sArena;            // [64][72], wave-private rows
    _Float16* __restrict__ sWt   = sArena + 4608;     // [64][136], wave-private rows
    _Float16* __restrict__ sMidA = sArena + 13312;    // wv*1056, wave-private

    const int t    = threadIdx.x;
    const int lane = t & 63;
    const int wv   = t >> 6;
    const int quad = lane >> 4;
    const int mm   = lane & 15;

    // XCD-chunked bijective swizzle
    const int orig = blockIdx.x;
    const int xcd  = orig & 7;
    constexpr int q = NEDGE_BLOCKS >> 3, r = NEDGE_BLOCKS & 7;   // 781, 2
    const int bid = (xcd < r ? xcd * (q + 1) : r * (q + 1) + (xcd - r) * q) + (orig >> 3);
    const int e0 = bid * 64;
    const int eb = wv * 16;

    // ---- (1) early global operands: fc1 fragments + se B-fragments ----
    f16x8 a_w1[4];
    f16x8 b_es = {};
    if (quad < 2) {
        const int myeid = sorted_eid[e0 + eb + mm];
        const f32x4* esp = (const f32x4*)edge_scalars + ((unsigned)myeid << 2) + (quad << 1);
        const f32x4 v0 = esp[0];
        const f32x4 v1 = esp[1];
        b_es[0] = (_Float16)v0[0]; b_es[1] = (_Float16)v0[1];
        b_es[2] = (_Float16)v0[2]; b_es[3] = (_Float16)v0[3];
        b_es[4] = (_Float16)v1[0]; b_es[5] = (_Float16)v1[1];
        b_es[6] = (_Float16)v1[2]; b_es[7] = (_Float16)v1[3];
        #pragma unroll
        for (int jt = 0; jt < 4; ++jt)
            a_w1[jt] = *(const f16x8*)&W1T_g[(jt * 16 + mm) * 16 + quad * 8];
    } else {
        #pragma unroll
        for (int jt = 0; jt < 4; ++jt) a_w1[jt] = (f16x8){};
    }
    f16x8 bt[8];                       // se-matmul B rows, L2-hot global
    #pragma unroll
    for (int ks = 0; ks < 8; ++ks)
        bt[ks] = *(const f16x8*)&BT_g[(mm & 7) * 264 + ks * 32 + quad * 8];

    // ---- (2) per-wave metadata self-stage (wave-private slices) ----
    if (lane < 16) {
        const int eid = sorted_eid[e0 + eb + lane];
        sEID[eb + lane] = eid;
        sSRC[eb + lane] = edge_src[eid];
        sDST[eb + lane] = edge_dst[eid];
        *(float4*)&sEA[(eb + lane) * 4] = ((const float4*)edge_attr)[eid];
    }
    WAVE_LDS_FENCE();

    // ---- (3) all 48 gathers upfront, pinned, 32-bit offsets ----
    const bool hi = lane >= 32;
    const int  u  = lane - 32;
    const int idxA = hi ? (32 + 3 * u) : lane;
    const int idxB = hi ? (33 + 3 * u) : lane;
    const int idxC = hi ? (34 + 3 * u) : lane;
    const int col1 = hi ? (96 + u) : lane;        // wD[u] | wA[l]
    const int col2 = hi ? (64 + u) : (32 + lane); // wC[u] | wB[l]

    float ga[4][4], gb[4][4], gc[4][4];
    #pragma unroll
    for (int b = 0; b < 4; ++b)
        #pragma unroll
        for (int i = 0; i < 4; ++i) {
            const unsigned off = (unsigned)sSRC[eb + b * 4 + i] << 7;
            ga[b][i] = (float)ws_h[off + idxA];
            gb[b][i] = (float)ws_h[off + idxB];
            gc[b][i] = (float)ws_h[off + idxC];
        }
    asm volatile("" ::: "memory");   // loads above cannot sink past this

    // ---- (4) fc1: h -> HT (wave-private rows) ----
    #pragma unroll
    for (int jt = 0; jt < 4; ++jt) {
        f32x4 d = {0.f, 0.f, 0.f, 0.f};
        d = __builtin_amdgcn_mfma_f32_16x16x32_f16(a_w1[jt], b_es, d, 0, 0, 0);
        f16x4 hv;
        hv[0] = (_Float16)__sinf(d[0] * FC1_S);
        hv[1] = (_Float16)__sinf(d[1] * FC1_S);
        hv[2] = (_Float16)__sinf(d[2] * FC1_S);
        hv[3] = (_Float16)__sinf(d[3] * FC1_S);
        *(f16x4*)&sHT[(eb + mm) * 72 + jt * 16 + quad * 4] = hv;
    }
    WAVE_LDS_FENCE();

    // ---- (5) fc2: A-fragments direct from global (L2-hot) ----
    f32x4 dacc[8];
    {
        const f16x8 b_lo = *(const f16x8*)&sHT[(eb + mm) * 72 + quad * 8];
        const f16x8 b_hi = *(const f16x8*)&sHT[(eb + mm) * 72 + 32 + quad * 8];
        #pragma unroll
        for (int ct = 0; ct < 8; ++ct) {
            const f16x8 a_lo = *(const f16x8*)&W2T_g[(ct * 16 + mm) * 72 + quad * 8];
            const f16x8 a_hi = *(const f16x8*)&W2T_g[(ct * 16 + mm) * 72 + 32 + quad * 8];
            f32x4 d = {0.f, 0.f, 0.f, 0.f};
            d = __builtin_amdgcn_mfma_f32_16x16x32_f16(a_lo, b_lo, d, 0, 0, 0);
            d = __builtin_amdgcn_mfma_f32_16x16x32_f16(a_hi, b_hi, d, 0, 0, 0);
            dacc[ct] = d;
        }
    }

    // ---- (6) Wt store (wave-private rows) ----
    #pragma unroll
    for (int ct = 0; ct < 8; ++ct) {
        f16x4 v;
        v[0] = (_Float16)(dacc[ct][0] * FC2_S);
        v[1] = (_Float16)(dacc[ct][1] * FC2_S);
        v[2] = (_Float16)(dacc[ct][2] * FC2_S);
        v[3] = (_Float16)(dacc[ct][3] * FC2_S);
        *(f16x4*)&sWt[(eb + mm) * 136 + ct * 16 + quad * 4] = v;
    }
    WAVE_LDS_FENCE();

    // ---- (7) message phase: 16 sorted edges in 4 batches ----
    int   cur = -1;
    float am0 = 0.f, axx = 0.f, ayy = 0.f, azz = 0.f;
    _Float16* __restrict__ myA = sMidA + wv * 1056;
    const _Float16* __restrict__ arow = myA + (mm & 3) * 264;

    #pragma unroll
    for (int b = 0; b < 4; ++b) {
        float w1b[4], w2b[4];
        #pragma unroll
        for (int i = 0; i < 4; ++i) {
            w1b[i] = (float)sWt[(eb + b * 4 + i) * 136 + col1];
            w2b[i] = (float)sWt[(eb + b * 4 + i) * 136 + col2];
        }
        #pragma unroll
        for (int i = 0; i < 4; ++i) {
            const int el  = eb + b * 4 + i;
            const int dst = sDST[el];
            const float ea0 = sEA[el * 4 + 0];
            const float e1x = sEA[el * 4 + 1];
            const float e1y = sEA[el * 4 + 2];
            const float e1z = sEA[el * 4 + 3];
            const float w1v = w1b[i];
            const float w2v = w2b[i];

            float mid0, m1x, m1y, m1z;
            if (!hi) {                       // lanes 0..31: mA, mB
                mid0 = w1v * ga[b][i] * ea0;
                const float wbg = w2v * ga[b][i];
                m1x = wbg * e1x; m1y = wbg * e1y; m1z = wbg * e1z;
            } else {                         // lanes 32..63: mD, mC
                const float dot = ga[b][i] * e1x + gb[b][i] * e1y + gc[b][i] * e1z;
                mid0 = w1v * dot * INV_SQRT3;
                const float wce = w2v * ea0;
                m1x = wce * ga[b][i]; m1y = wce * gb[b][i]; m1z = wce * gc[b][i];
            }

            if (dst != cur) {               // segment flush (dst wave-uniform)
                if (cur >= 0) {
                    float* np_ = nacc + ((unsigned)cur << 8);
                    atomicAdd(np_ + lane, am0);
                    atomicAdd(np_ + 64 + lane, axx);
                    atomicAdd(np_ + 128 + lane, ayy);
                    atomicAdd(np_ + 192 + lane, azz);
                }
                cur = dst; am0 = axx = ayy = azz = 0.f;
            }
            am0 += mid0; axx += m1x; ayy += m1y; azz += m1z;

            // mid -> A-tile row i, k = 4*lane + {0,1,2,3}
            f16x4 mv;
            mv[0] = (_Float16)mid0; mv[1] = (_Float16)m1x;
            mv[2] = (_Float16)m1y;  mv[3] = (_Float16)m1z;
            *(f16x4*)&myA[i * 264 + 4 * lane] = mv;
        }

        // se matmul: [4e x 256k] x [256k x 8c], K-loop of 8 MFMAs (B in regs)
        f32x4 d = {0.f, 0.f, 0.f, 0.f};
        #pragma unroll
        for (int ks = 0; ks < 8; ++ks) {
            const f16x8 a = *(const f16x8*)&arow[ks * 32 + quad * 8];
            d = __builtin_amdgcn_mfma_f32_16x16x32_f16(a, bt[ks], d, 0, 0, 0);
        }
        if (lane < 8) {                 // quad 0: reg r = edge b*4+r, col = lane
            float4 f4; f4.x = d[0]; f4.y = d[1]; f4.z = d[2]; f4.w = d[3];
            *(float4*)&sDep[wv][lane * 4] = f4;
        }
        if (lane < 4) {                 // lane = edge within batch
            const int el = eb + b * 4 + lane;
            const float c0 = sDep[wv][ 0 + lane], c1 = sDep[wv][ 4 + lane];
            const float c2 = sDep[wv][ 8 + lane], c3 = sDep[wv][12 + lane];
            const float c4 = sDep[wv][16 + lane], c5 = sDep[wv][20 + lane];
            const float c6 = sDep[wv][24 + lane], c7 = sDep[wv][28 + lane];
            const float ea0 = sEA[el * 4 + 0];
            const float e1x = sEA[el * 4 + 1];
            const float e1y = sEA[el * 4 + 2];
            const float e1z = sEA[el * 4 + 3];
            const float s0 = c0 * ea0 + (c3 * e1x + c5 * e1y + c7 * e1z) * INV_SQRT3;
            float4 o;
            o.x = ea0 + s0 * S_SE * INV_NN;
            o.y = e1x + (c1 * e1x + c2 * ea0) * S_SE * INV_NN;
            o.z = e1y + (c1 * e1y + c4 * ea0) * S_SE * INV_NN;
            o.w = e1z + (c1 * e1z + c6 * ea0) * S_SE * INV_NN;
            *(float4*)&edge_out[(unsigned)sEID[el] << 2] = o;
        }
    }
    if (cur >= 0) {
        float* np_ = nacc + ((unsigned)cur << 8);
        atomicAdd(np_ + lane, am0);
        atomicAdd(np_ + 64 + lane, axx);
        atomicAdd(np_ + 128 + lane, ayy);
        atomicAdd(np_ + 192 + lane, azz);
    }
}

// ---------------------------------------------------------------------------
// Kernel C: per-node post (r9 form); 8 nodes/block. nacc layout
// [mid0(64) | c*64+u]; out RMW adds to out_self written by pre_hist.
// ---------------------------------------------------------------------------
__global__ __launch_bounds__(128) void node_post_kernel(
    const float* __restrict__ nacc, const float* __restrict__ node_attr,
    const float* __restrict__ w_lin2_0, const float* __restrict__ w_lin2_1,
    const float* __restrict__ w_alpha, float* __restrict__ out)
{
    const int n0 = blockIdx.x * 8, t = threadIdx.x;
    __shared__ __align__(16) float sn[8 * 256];
    __shared__ float salpha[8];
    const float4* src = (const float4*)(nacc + (size_t)n0 * 256);
    #pragma unroll
    for (int i = 0; i < 4; ++i) ((float4*)sn)[t + i * 128] = src[t + i * 128];
    __syncthreads();

    if (t < 64) {
        const float wa = w_alpha[t];
        #pragma unroll
        for (int k = 0; k < 8; ++k) {
            const float r = wave_reduce_dpp(sn[k * 256 + t] * wa);
            if (t == 0) salpha[k] = r;
        }
    }
    __syncthreads();

    float wcol[64];
    int xoff = 0;
    if (t < 32) {
        #pragma unroll
        for (int u = 0; u < 64; ++u) wcol[u] = w_lin2_0[u * 32 + t];
    } else {
        const int j = t - 32; const int w = j / 3; const int m = j % 3;
        xoff = 64 + m * 64;
        #pragma unroll
        for (int u = 0; u < 64; ++u) wcol[u] = w_lin2_1[u * 32 + w];
    }
    #pragma unroll
    for (int k = 0; k < 8; ++k) {
        const float* xb = sn + k * 256 + xoff;
        float acc = 0.f;
        #pragma unroll
        for (int u4 = 0; u4 < 16; ++u4) {
            const f32x4 xv = *(const f32x4*)&xb[u4 * 4];
            acc += xv[0] * wcol[u4 * 4 + 0];
            acc += xv[1] * wcol[u4 * 4 + 1];
            acc += xv[2] * wcol[u4 * 4 + 2];
            acc += xv[3] * wcol[u4 * 4 + 3];
        }
        const float a  = node_attr[n0 + k];
        const float sc = a * S_MID * INV_NN;
        const size_t o = (size_t)(n0 + k) * 128 + t;
        out[o] = out[o] + (salpha[k] * sc) * (acc * sc);
    }
}

extern "C" void kernel_launch(void* const* d_in, const int* in_sizes, int n_in,
                              void* d_out, int out_size, void* d_ws, size_t ws_size,
                              hipStream_t stream)
{
    const float* node_input   = (const float*)d_in[0];
    const float* node_attr    = (const float*)d_in[1];
    const int*   edge_src     = (const int*)d_in[2];
    const int*   edge_dst     = (const int*)d_in[3];
    const float* edge_attr    = (const float*)d_in[4];
    const float* edge_scalars = (const float*)d_in[5];
    const float* w_sc0        = (const float*)d_in[6];
    const float* w_sc1        = (const float*)d_in[7];
    const float* w_lin1_0     = (const float*)d_in[8];
    const float* w_lin1_1     = (const float*)d_in[9];
    const float* fc_w1        = (const float*)d_in[10];
    const float* fc_w2        = (const float*)d_in[11];
    const float* w_lin2_0     = (const float*)d_in[12];
    const float* w_lin2_1     = (const float*)d_in[13];
    const float* w_alpha      = (const float*)d_in[14];
    const float* w_se0a       = (const float*)d_in[15];
    const float* w_se0b       = (const float*)d_in[16];
    const float* w_se1a       = (const float*)d_in[17];
    const float* w_se1b       = (const float*)d_in[18];

    float* out      = (float*)d_out;
    float* edge_out = out + (size_t)N_NODES * 128;

    _Float16* ws_h = (_Float16*)d_ws;                          // N*128 halfs
    float* nacc   = (float*)((char*)d_ws + (size_t)N_NODES * 128 * 4);
    int*   counts = (int*)(nacc + (size_t)N_NODES * 256);      // N
    int*   cursor = counts + N_NODES;                          // N
    int*   sid    = cursor + N_NODES;                          // E
    int*   bsum   = sid + E_EDGES;                             // 64
    _Float16* W2T_g = (_Float16*)(bsum + 64);                  // 9216 halfs
    _Float16* W1T_g = W2T_g + 9216;                            // 1024 halfs
    _Float16* BT_g  = W1T_g + 1024;                            // 2112 halfs
    int* sync_cnt   = (int*)(BT_g + 2112);                     // 1

    hipMemsetAsync(counts, 0, N_NODES * sizeof(int), stream);  // counts only

    pre_hist_kernel<<<NPRE_BLOCKS + NHIST_BLOCKS, 256, 0, stream>>>(
        node_input, node_attr, w_sc0, w_sc1, w_lin1_0, w_lin1_1, out, ws_h,
        edge_dst, counts, nacc, sync_cnt);

    scan_fused_kernel<<<NSCAN_BLOCKS, 1024, 0, stream>>>(
        counts, cursor, bsum, sync_cnt,
        fc_w1, fc_w2, w_se0a, w_se0b, w_se1a, w_se1b, W2T_g, W1T_g, BT_g);

    scatter_kernel<<<(E_EDGES + 255) / 256, 256, 0, stream>>>(edge_dst, cursor, sid);

    edge_kernel<<<NEDGE_BLOCKS, 256, 0, stream>>>(
        ws_h, edge_src, edge_dst, edge_attr, edge_scalars, W2T_g, W1T_g, BT_g,
        sid, nacc, edge_out);

    node_post_kernel<<<N_NODES / 8, 128, 0, stream>>>(
        nacc, node_attr, w_lin2_0, w_lin2_1, w_alpha, out);
}

// Round 12
// 345.261 us; speedup vs baseline: 1.1230x; 1.1230x over previous
//
#include <hip/hip_runtime.h>
#include <math.h>

#define N_NODES 50000
#define E_EDGES 400000
#define NPRE_BLOCKS 6250          // N_NODES/8
#define NHIST_BLOCKS 1563         // ceil(E/256)
#define NEDGE_BLOCKS 6250         // E_EDGES/64

typedef _Float16 f16x2 __attribute__((ext_vector_type(2)));
typedef _Float16 f16x4 __attribute__((ext_vector_type(4)));
typedef _Float16 f16x8 __attribute__((ext_vector_type(8)));
typedef float    f32x4 __attribute__((ext_vector_type(4)));

static constexpr float S_IN      = 0.17677669529663687f;   // 1/sqrt(32)
static constexpr float S_MID     = 0.125f;                 // 1/sqrt(64)
static constexpr float S_SE      = 0.08838834764831843f;   // 1/sqrt(128)
static constexpr float INV_NN    = 0.35355339059327373f;   // 1/sqrt(8)
static constexpr float INV_SQRT3 = 0.5773502691896258f;
static constexpr float FC1_S     = 0.25f;                  // 1/sqrt(16)
static constexpr float FC2_S     = 0.125f;                 // 1/sqrt(64)

// Wave-local LDS ordering (one instruction stream per wave -> lgkmcnt(0)
// orders this wave's ds_write -> ds_read). No s_barrier.
#define WAVE_LDS_FENCE() asm volatile("s_waitcnt lgkmcnt(0)" ::: "memory")

// 64-lane sum via DPP: row_shr 1/2/4/8, bcast15, bcast31.
__device__ inline float wave_reduce_dpp(float v) {
    int x;
    x = __builtin_amdgcn_update_dpp(0, __float_as_int(v), 0x111, 0xf, 0xf, true); v += __int_as_float(x);
    x = __builtin_amdgcn_update_dpp(0, __float_as_int(v), 0x112, 0xf, 0xf, true); v += __int_as_float(x);
    x = __builtin_amdgcn_update_dpp(0, __float_as_int(v), 0x114, 0xf, 0xf, true); v += __int_as_float(x);
    x = __builtin_amdgcn_update_dpp(0, __float_as_int(v), 0x118, 0xf, 0xf, true); v += __int_as_float(x);
    x = __builtin_amdgcn_update_dpp(0, __float_as_int(v), 0x142, 0xa, 0xf, true); v += __int_as_float(x);
    x = __builtin_amdgcn_update_dpp(0, __float_as_int(v), 0x143, 0xc, 0xf, true); v += __int_as_float(x);
    return __int_as_float(__builtin_amdgcn_readlane(__float_as_int(v), 63));
}

// ---------------------------------------------------------------------------
// Kernel A (fused): blocks [0,NPRE) per-node precompute (+ zero its nacc
// rows); rest: dst histogram + edge_scalars->f16. [358us-verified form]
// ---------------------------------------------------------------------------
__global__ __launch_bounds__(256) void pre_hist_kernel(
    const float* __restrict__ node_input, const float* __restrict__ node_attr,
    const float* __restrict__ w_sc0, const float* __restrict__ w_sc1,
    const float* __restrict__ w_lin1_0, const float* __restrict__ w_lin1_1,
    float* __restrict__ out_self, _Float16* __restrict__ ws_h,
    const int* __restrict__ edge_dst, int* __restrict__ counts,
    const float* __restrict__ edge_scalars, _Float16* __restrict__ ES_h,
    float* __restrict__ nacc)
{
    const int t = threadIdx.x;
    if (blockIdx.x >= NPRE_BLOCKS) {          // histogram + ES convert role
        const int e = (blockIdx.x - NPRE_BLOCKS) * 256 + t;
        if (e < E_EDGES) {
            atomicAdd(&counts[edge_dst[e]], 1);
            const float4* s4 = (const float4*)edge_scalars + (size_t)e * 4;
            _Float16* dp = ES_h + (size_t)e * 16;
            #pragma unroll
            for (int i = 0; i < 4; ++i) {
                const float4 v = s4[i];
                f16x4 p = {(_Float16)v.x, (_Float16)v.y, (_Float16)v.z, (_Float16)v.w};
                *(f16x4*)&dp[i * 4] = p;
            }
        }
        return;
    }
    const int n0 = blockIdx.x * 8;
    __shared__ __align__(16) float sx[8 * 128];   // [k][ x0(32) | m*32+u (96) ]
    __shared__ float sa[8];
    {   // staged transpose: x0 straight, x1 scattered to [m][u]
        const int k = t >> 5, q = t & 31;
        const float4 v = ((const float4*)(node_input + (size_t)n0 * 128))[t];
        if (q < 8) {
            *(float4*)&sx[k * 128 + q * 4] = v;
        } else {
            const int base = q * 4 - 32;          // x1 element index u*3+m
            const float vv[4] = {v.x, v.y, v.z, v.w};
            #pragma unroll
            for (int j = 0; j < 4; ++j) {
                const int uj = (base + j) / 3, mj = (base + j) % 3;
                sx[k * 128 + 32 + mj * 32 + uj] = vv[j];
            }
        }
    }
    {   // zero this block's nacc rows
        float4* nz = (float4*)(nacc + (size_t)n0 * 256);
        const float4 z4 = {0.f, 0.f, 0.f, 0.f};
        nz[t] = z4; nz[t + 256] = z4;
    }
    if (t < 8) sa[t] = node_attr[n0 + t];
    __syncthreads();

    const int half = t >> 7;
    const int idx  = t & 127;
    float wcol[32];
    int xoff = 0;
    if (idx < 32) {
        const float* __restrict__ W = half ? w_lin1_0 : w_sc0;
        #pragma unroll
        for (int u = 0; u < 32; ++u) wcol[u] = W[u * 32 + idx];
    } else {
        const float* __restrict__ W = half ? w_lin1_1 : w_sc1;
        const int j = idx - 32;
        const int w = j / 3; const int m = j % 3;
        xoff = 32 + m * 32;
        #pragma unroll
        for (int u = 0; u < 32; ++u) wcol[u] = W[u * 32 + w];
    }
    #pragma unroll
    for (int k = 0; k < 8; ++k) {
        const float* xb = sx + k * 128 + xoff;
        float acc = 0.f;
        #pragma unroll
        for (int u4 = 0; u4 < 8; ++u4) {          // broadcast f32x4 reads
            const f32x4 xv = *(const f32x4*)&xb[u4 * 4];
            acc += xv[0] * wcol[u4 * 4 + 0];
            acc += xv[1] * wcol[u4 * 4 + 1];
            acc += xv[2] * wcol[u4 * 4 + 2];
            acc += xv[3] * wcol[u4 * 4 + 3];
        }
        const float v = acc * sa[k] * S_IN;
        if (half) ws_h[(size_t)(n0 + k) * 128 + idx] = (_Float16)v;
        else      out_self[(size_t)(n0 + k) * 128 + idx] = v;
    }
}

// ---------------------------------------------------------------------------
// Sort by dst: DPP wave-scan -> fixup -> scatter (split form — the fused
// gsync variant measured +20us across r10/r11).
// Block 49 is the one-time weight-prep block.
// ---------------------------------------------------------------------------
__global__ __launch_bounds__(1024) void scan_block_kernel(
    const int* __restrict__ counts, int* __restrict__ cursor, int* __restrict__ bsum,
    const float* __restrict__ fc_w1, const float* __restrict__ fc_w2,
    const float* __restrict__ w_se0a, const float* __restrict__ w_se0b,
    const float* __restrict__ w_se1a, const float* __restrict__ w_se1b,
    _Float16* __restrict__ W2T_g, _Float16* __restrict__ W1T_g,
    _Float16* __restrict__ BT_g)
{
    const int t = threadIdx.x;
    if (blockIdx.x == 49) {                 // weight-prep block
        for (int u = t; u < 8192; u += 1024) {
            const int k = u >> 7, c = u & 127;
            W2T_g[c * 72 + k] = (_Float16)fc_w2[u];
        }
        {                                    // pad k=64..71
            W2T_g[(t >> 3) * 72 + 64 + (t & 7)] = (_Float16)0.f;
        }
        {                                    // W1T[j][k], k<16
            const int j = t >> 4, k = t & 15;
            W1T_g[t] = (_Float16)fc_w1[k * 64 + j];
        }
        for (int u = t; u < 2112; u += 1024) BT_g[u] = (_Float16)0.f;
        __syncthreads();
        if (t < 256) {   // col 2p: {se0a|se1b} on comp p; col 2p+1: {se1a|se0b}
            const int uu = t & 63, p = t >> 6;
            const float ev = (p == 0) ? w_se0a[uu] : w_se1b[uu];
            const float ov = (p == 0) ? w_se1a[uu] : w_se0b[uu];
            BT_g[(2 * p) * 264 + 4 * uu + p]     = (_Float16)ev;
            BT_g[(2 * p + 1) * 264 + 4 * uu + p] = (_Float16)ov;
        }
        return;
    }
    const int idx = blockIdx.x * 1024 + t;
    const int c   = (idx < N_NODES) ? counts[idx] : 0;
    int v = c, x;
    x = __builtin_amdgcn_update_dpp(0, v, 0x111, 0xf, 0xf, true); v += x;
    x = __builtin_amdgcn_update_dpp(0, v, 0x112, 0xf, 0xf, true); v += x;
    x = __builtin_amdgcn_update_dpp(0, v, 0x114, 0xf, 0xf, true); v += x;
    x = __builtin_amdgcn_update_dpp(0, v, 0x118, 0xf, 0xf, true); v += x;
    x = __builtin_amdgcn_update_dpp(0, v, 0x142, 0xa, 0xf, true); v += x;
    x = __builtin_amdgcn_update_dpp(0, v, 0x143, 0xc, 0xf, true); v += x;
    __shared__ int swv[16], sex[16];
    const int wid = t >> 6;
    if ((t & 63) == 63) swv[wid] = v;
    __syncthreads();
    if (t < 16) {
        int a = 0;
        for (int j = 0; j < t; ++j) a += swv[j];
        sex[t] = a;
        if (t == 15) bsum[blockIdx.x] = a + swv[15];
    }
    __syncthreads();
    if (idx < N_NODES) cursor[idx] = v - c + sex[wid];   // block-local exclusive
}

__global__ __launch_bounds__(1024) void scan_fixup_kernel(
    int* __restrict__ cursor, const int* __restrict__ bsum)
{
    __shared__ int boff_s;
    const int t = threadIdx.x;
    if (t < 64) {
        int v = (t < (int)blockIdx.x) ? bsum[t] : 0;   // blockIdx <= 48 < 64
        #pragma unroll
        for (int off = 32; off >= 1; off >>= 1) v += __shfl_down(v, off, 64);
        if (t == 0) boff_s = v;
    }
    __syncthreads();
    const int idx = blockIdx.x * 1024 + t;
    if (idx < N_NODES) cursor[idx] += boff_s;
}

__global__ __launch_bounds__(256) void scatter_kernel(
    const int* __restrict__ edge_dst, int* __restrict__ cursor,
    int* __restrict__ sorted_eid)
{
    const int e = blockIdx.x * 256 + threadIdx.x;
    if (e < E_EDGES) {
        const int p = atomicAdd(&cursor[edge_dst[e]], 1);
        sorted_eid[p] = e;
    }
}

// ---------------------------------------------------------------------------
// Kernel B: per-edge, dst-sorted, 64 edges/block, 4 waves, BARRIER-FREE.
// 358us-verified r9 form (ES_h f16 + 32-bit addressing, (256,4)). ONE
// ordering tweak: bt[8] loads moved AFTER the gather pin — they are only
// needed in the message phase, and issuing them before the
// sorted_eid->src->gather chain delayed the critical gathers by 8 VMEM slots.
// LDS: HT[64][72]@0 | Wt[64][136]@4608h | midA 4x1056h @13312h = 37.4KB
// ---------------------------------------------------------------------------
__global__ __launch_bounds__(256, 4) void edge_kernel(
    const _Float16* __restrict__ ws_h,
    const int* __restrict__ edge_src, const int* __restrict__ edge_dst,
    const float* __restrict__ edge_attr, const _Float16* __restrict__ ES_h,
    const _Float16* __restrict__ W2T_g, const _Float16* __restrict__ W1T_g,
    const _Float16* __restrict__ BT_g,
    const int* __restrict__ sorted_eid,
    float* __restrict__ nacc, float* __restrict__ edge_out)
{
    __shared__ __align__(16) _Float16 sArena[17536];
    __shared__ __align__(16) float sEA[64 * 4];
    __shared__ __align__(16) float sDep[4][36];
    __shared__ int sSRC[64];
    __shared__ int sDST[64];
    __shared__ int sEID[64];

    _Float16* __restrict__ sHT   = sArena;            // [64][72], wave-private rows
    _Float16* __restrict__ sWt   = sArena + 4608;     // [64][136], wave-private rows
    _Float16* __restrict__ sMidA = sArena + 13312;    // wv*1056, wave-private

    const int t    = threadIdx.x;
    const int lane = t & 63;
    const int wv   = t >> 6;
    const int quad = lane >> 4;
    const int mm   = lane & 15;

    // XCD-chunked bijective swizzle
    const int orig = blockIdx.x;
    const int xcd  = orig & 7;
    constexpr int q = NEDGE_BLOCKS >> 3, r = NEDGE_BLOCKS & 7;   // 781, 2
    const int bid = (xcd < r ? xcd * (q + 1) : r * (q + 1) + (xcd - r) * q) + (orig >> 3);
    const int e0 = bid * 64;
    const int eb = wv * 16;

    // ---- (1) early global operands for fc1 ----
    f16x8 a_w1[4];
    f16x8 b_es = {};
    if (quad < 2) {
        const int myeid = sorted_eid[e0 + eb + mm];
        b_es = *(const f16x8*)&ES_h[((unsigned)myeid << 4) + quad * 8];
        #pragma unroll
        for (int jt = 0; jt < 4; ++jt)
            a_w1[jt] = *(const f16x8*)&W1T_g[(jt * 16 + mm) * 16 + quad * 8];
    } else {
        #pragma unroll
        for (int jt = 0; jt < 4; ++jt) a_w1[jt] = (f16x8){};
    }

    // ---- (2) per-wave metadata self-stage (wave-private slices) ----
    if (lane < 16) {
        const int eid = sorted_eid[e0 + eb + lane];
        sEID[eb + lane] = eid;
        sSRC[eb + lane] = edge_src[eid];
        sDST[eb + lane] = edge_dst[eid];
        *(float4*)&sEA[(eb + lane) * 4] = ((const float4*)edge_attr)[eid];
    }
    WAVE_LDS_FENCE();

    // ---- (3) all 48 gathers upfront, pinned, 32-bit offsets ----
    const bool hi = lane >= 32;
    const int  u  = lane - 32;
    const int idxA = hi ? (32 + 3 * u) : lane;
    const int idxB = hi ? (33 + 3 * u) : lane;
    const int idxC = hi ? (34 + 3 * u) : lane;
    const int col1 = hi ? (96 + u) : lane;        // wD[u] | wA[l]
    const int col2 = hi ? (64 + u) : (32 + lane); // wC[u] | wB[l]

    float ga[4][4], gb[4][4], gc[4][4];
    #pragma unroll
    for (int b = 0; b < 4; ++b)
        #pragma unroll
        for (int i = 0; i < 4; ++i) {
            const unsigned off = (unsigned)sSRC[eb + b * 4 + i] << 7;
            ga[b][i] = (float)ws_h[off + idxA];
            gb[b][i] = (float)ws_h[off + idxB];
            gc[b][i] = (float)ws_h[off + idxC];
        }
    asm volatile("" ::: "memory");   // loads above cannot sink past this

    // ---- se-matmul B rows (message phase only): issued after the gather
    //      chain, latency hides under fc1+fc2 ----
    f16x8 bt[8];
    #pragma unroll
    for (int ks = 0; ks < 8; ++ks)
        bt[ks] = *(const f16x8*)&BT_g[(mm & 7) * 264 + ks * 32 + quad * 8];

    // ---- (4) fc1: h -> HT (wave-private rows) ----
    #pragma unroll
    for (int jt = 0; jt < 4; ++jt) {
        f32x4 d = {0.f, 0.f, 0.f, 0.f};
        d = __builtin_amdgcn_mfma_f32_16x16x32_f16(a_w1[jt], b_es, d, 0, 0, 0);
        f16x4 hv;
        hv[0] = (_Float16)__sinf(d[0] * FC1_S);
        hv[1] = (_Float16)__sinf(d[1] * FC1_S);
        hv[2] = (_Float16)__sinf(d[2] * FC1_S);
        hv[3] = (_Float16)__sinf(d[3] * FC1_S);
        *(f16x4*)&sHT[(eb + mm) * 72 + jt * 16 + quad * 4] = hv;
    }
    WAVE_LDS_FENCE();

    // ---- (5) fc2: A-fragments direct from global (L2-hot) ----
    f32x4 dacc[8];
    {
        const f16x8 b_lo = *(const f16x8*)&sHT[(eb + mm) * 72 + quad * 8];
        const f16x8 b_hi = *(const f16x8*)&sHT[(eb + mm) * 72 + 32 + quad * 8];
        #pragma unroll
        for (int ct = 0; ct < 8; ++ct) {
            const f16x8 a_lo = *(const f16x8*)&W2T_g[(ct * 16 + mm) * 72 + quad * 8];
            const f16x8 a_hi = *(const f16x8*)&W2T_g[(ct * 16 + mm) * 72 + 32 + quad * 8];
            f32x4 d = {0.f, 0.f, 0.f, 0.f};
            d = __builtin_amdgcn_mfma_f32_16x16x32_f16(a_lo, b_lo, d, 0, 0, 0);
            d = __builtin_amdgcn_mfma_f32_16x16x32_f16(a_hi, b_hi, d, 0, 0, 0);
            dacc[ct] = d;
        }
    }

    // ---- (6) Wt store (wave-private rows) ----
    #pragma unroll
    for (int ct = 0; ct < 8; ++ct) {
        f16x4 v;
        v[0] = (_Float16)(dacc[ct][0] * FC2_S);
        v[1] = (_Float16)(dacc[ct][1] * FC2_S);
        v[2] = (_Float16)(dacc[ct][2] * FC2_S);
        v[3] = (_Float16)(dacc[ct][3] * FC2_S);
        *(f16x4*)&sWt[(eb + mm) * 136 + ct * 16 + quad * 4] = v;
    }
    WAVE_LDS_FENCE();

    // ---- (7) message phase: 16 sorted edges in 4 batches ----
    int   cur = -1;
    float am0 = 0.f, axx = 0.f, ayy = 0.f, azz = 0.f;
    _Float16* __restrict__ myA = sMidA + wv * 1056;
    const _Float16* __restrict__ arow = myA + (mm & 3) * 264;

    #pragma unroll
    for (int b = 0; b < 4; ++b) {
        float w1b[4], w2b[4];
        #pragma unroll
        for (int i = 0; i < 4; ++i) {
            w1b[i] = (float)sWt[(eb + b * 4 + i) * 136 + col1];
            w2b[i] = (float)sWt[(eb + b * 4 + i) * 136 + col2];
        }
        #pragma unroll
        for (int i = 0; i < 4; ++i) {
            const int el  = eb + b * 4 + i;
            const int dst = sDST[el];
            const float ea0 = sEA[el * 4 + 0];
            const float e1x = sEA[el * 4 + 1];
            const float e1y = sEA[el * 4 + 2];
            const float e1z = sEA[el * 4 + 3];
            const float w1v = w1b[i];
            const float w2v = w2b[i];

            float mid0, m1x, m1y, m1z;
            if (!hi) {                       // lanes 0..31: mA, mB
                mid0 = w1v * ga[b][i] * ea0;
                const float wbg = w2v * ga[b][i];
                m1x = wbg * e1x; m1y = wbg * e1y; m1z = wbg * e1z;
            } else {                         // lanes 32..63: mD, mC
                const float dot = ga[b][i] * e1x + gb[b][i] * e1y + gc[b][i] * e1z;
                mid0 = w1v * dot * INV_SQRT3;
                const float wce = w2v * ea0;
                m1x = wce * ga[b][i]; m1y = wce * gb[b][i]; m1z = wce * gc[b][i];
            }

            if (dst != cur) {               // segment flush (dst wave-uniform)
                if (cur >= 0) {
                    float* np_ = nacc + ((unsigned)cur << 8);
                    atomicAdd(np_ + lane, am0);
                    atomicAdd(np_ + 64 + lane, axx);
                    atomicAdd(np_ + 128 + lane, ayy);
                    atomicAdd(np_ + 192 + lane, azz);
                }
                cur = dst; am0 = axx = ayy = azz = 0.f;
            }
            am0 += mid0; axx += m1x; ayy += m1y; azz += m1z;

            // mid -> A-tile row i, k = 4*lane + {0,1,2,3}
            f16x4 mv;
            mv[0] = (_Float16)mid0; mv[1] = (_Float16)m1x;
            mv[2] = (_Float16)m1y;  mv[3] = (_Float16)m1z;
            *(f16x4*)&myA[i * 264 + 4 * lane] = mv;
        }

        // se matmul: [4e x 256k] x [256k x 8c], K-loop of 8 MFMAs (B in regs)
        f32x4 d = {0.f, 0.f, 0.f, 0.f};
        #pragma unroll
        for (int ks = 0; ks < 8; ++ks) {
            const f16x8 a = *(const f16x8*)&arow[ks * 32 + quad * 8];
            d = __builtin_amdgcn_mfma_f32_16x16x32_f16(a, bt[ks], d, 0, 0, 0);
        }
        if (lane < 8) {                 // quad 0: reg r = edge b*4+r, col = lane
            float4 f4; f4.x = d[0]; f4.y = d[1]; f4.z = d[2]; f4.w = d[3];
            *(float4*)&sDep[wv][lane * 4] = f4;
        }
        if (lane < 4) {                 // lane = edge within batch
            const int el = eb + b * 4 + lane;
            const float c0 = sDep[wv][ 0 + lane], c1 = sDep[wv][ 4 + lane];
            const float c2 = sDep[wv][ 8 + lane], c3 = sDep[wv][12 + lane];
            const float c4 = sDep[wv][16 + lane], c5 = sDep[wv][20 + lane];
            const float c6 = sDep[wv][24 + lane], c7 = sDep[wv][28 + lane];
            const float ea0 = sEA[el * 4 + 0];
            const float e1x = sEA[el * 4 + 1];
            const float e1y = sEA[el * 4 + 2];
            const float e1z = sEA[el * 4 + 3];
            const float s0 = c0 * ea0 + (c3 * e1x + c5 * e1y + c7 * e1z) * INV_SQRT3;
            float4 o;
            o.x = ea0 + s0 * S_SE * INV_NN;
            o.y = e1x + (c1 * e1x + c2 * ea0) * S_SE * INV_NN;
            o.z = e1y + (c1 * e1y + c4 * ea0) * S_SE * INV_NN;
            o.w = e1z + (c1 * e1z + c6 * ea0) * S_SE * INV_NN;
            *(float4*)&edge_out[(unsigned)sEID[el] << 2] = o;
        }
    }
    if (cur >= 0) {
        float* np_ = nacc + ((unsigned)cur << 8);
        atomicAdd(np_ + lane, am0);
        atomicAdd(np_ + 64 + lane, axx);
        atomicAdd(np_ + 128 + lane, ayy);
        atomicAdd(np_ + 192 + lane, azz);
    }
}

// ---------------------------------------------------------------------------
// Kernel C: per-node post; 8 nodes/block. nacc layout [mid0(64) | c*64+u].
// ---------------------------------------------------------------------------
__global__ __launch_bounds__(128) void node_post_kernel(
    const float* __restrict__ nacc, const float* __restrict__ node_attr,
    const float* __restrict__ w_lin2_0, const float* __restrict__ w_lin2_1,
    const float* __restrict__ w_alpha, float* __restrict__ out)
{
    const int n0 = blockIdx.x * 8, t = threadIdx.x;
    __shared__ __align__(16) float sn[8 * 256];
    __shared__ float salpha[8];
    const float4* src = (const float4*)(nacc + (size_t)n0 * 256);
    #pragma unroll
    for (int i = 0; i < 4; ++i) ((float4*)sn)[t + i * 128] = src[t + i * 128];
    __syncthreads();

    if (t < 64) {
        const float wa = w_alpha[t];
        #pragma unroll
        for (int k = 0; k < 8; ++k) {
            const float r = wave_reduce_dpp(sn[k * 256 + t] * wa);
            if (t == 0) salpha[k] = r;
        }
    }
    __syncthreads();

    float wcol[64];
    int xoff = 0;
    if (t < 32) {
        #pragma unroll
        for (int u = 0; u < 64; ++u) wcol[u] = w_lin2_0[u * 32 + t];
    } else {
        const int j = t - 32; const int w = j / 3; const int m = j % 3;
        xoff = 64 + m * 64;
        #pragma unroll
        for (int u = 0; u < 64; ++u) wcol[u] = w_lin2_1[u * 32 + w];
    }
    #pragma unroll
    for (int k = 0; k < 8; ++k) {
        const float* xb = sn + k * 256 + xoff;
        float acc = 0.f;
        #pragma unroll
        for (int u4 = 0; u4 < 16; ++u4) {
            const f32x4 xv = *(const f32x4*)&xb[u4 * 4];
            acc += xv[0] * wcol[u4 * 4 + 0];
            acc += xv[1] * wcol[u4 * 4 + 1];
            acc += xv[2] * wcol[u4 * 4 + 2];
            acc += xv[3] * wcol[u4 * 4 + 3];
        }
        const float a  = node_attr[n0 + k];
        const float sc = a * S_MID * INV_NN;
        const size_t o = (size_t)(n0 + k) * 128 + t;
        out[o] = out[o] + (salpha[k] * sc) * (acc * sc);
    }
}

extern "C" void kernel_launch(void* const* d_in, const int* in_sizes, int n_in,
                              void* d_out, int out_size, void* d_ws, size_t ws_size,
                              hipStream_t stream)
{
    const float* node_input   = (const float*)d_in[0];
    const float* node_attr    = (const float*)d_in[1];
    const int*   edge_src     = (const int*)d_in[2];
    const int*   edge_dst     = (const int*)d_in[3];
    const float* edge_attr    = (const float*)d_in[4];
    const float* edge_scalars = (const float*)d_in[5];
    const float* w_sc0        = (const float*)d_in[6];
    const float* w_sc1        = (const float*)d_in[7];
    const float* w_lin1_0     = (const float*)d_in[8];
    const float* w_lin1_1     = (const float*)d_in[9];
    const float* fc_w1        = (const float*)d_in[10];
    const float* fc_w2        = (const float*)d_in[11];
    const float* w_lin2_0     = (const float*)d_in[12];
    const float* w_lin2_1     = (const float*)d_in[13];
    const float* w_alpha      = (const float*)d_in[14];
    const float* w_se0a       = (const float*)d_in[15];
    const float* w_se0b       = (const float*)d_in[16];
    const float* w_se1a       = (const float*)d_in[17];
    const float* w_se1b       = (const float*)d_in[18];

    float* out      = (float*)d_out;
    float* edge_out = out + (size_t)N_NODES * 128;

    _Float16* ws_h = (_Float16*)d_ws;                          // N*128 halfs
    _Float16* ES_h = ws_h + (size_t)N_NODES * 128;             // E*16 halfs
    float* nacc   = (float*)((char*)d_ws + (size_t)N_NODES * 128 * 4);
    int*   counts = (int*)(nacc + (size_t)N_NODES * 256);      // N
    int*   cursor = counts + N_NODES;                          // N
    int*   sid    = cursor + N_NODES;                          // E
    int*   bsum   = sid + E_EDGES;                             // 64
    _Float16* W2T_g = (_Float16*)(bsum + 64);                  // 9216 halfs
    _Float16* W1T_g = W2T_g + 9216;                            // 1024 halfs
    _Float16* BT_g  = W1T_g + 1024;                            // 2112 halfs

    hipMemsetAsync(counts, 0, N_NODES * sizeof(int), stream);  // counts only

    pre_hist_kernel<<<NPRE_BLOCKS + NHIST_BLOCKS, 256, 0, stream>>>(
        node_input, node_attr, w_sc0, w_sc1, w_lin1_0, w_lin1_1, out, ws_h,
        edge_dst, counts, edge_scalars, ES_h, nacc);

    scan_block_kernel<<<50, 1024, 0, stream>>>(counts, cursor, bsum,
        fc_w1, fc_w2, w_se0a, w_se0b, w_se1a, w_se1b, W2T_g, W1T_g, BT_g);
    scan_fixup_kernel<<<49, 1024, 0, stream>>>(cursor, bsum);
    scatter_kernel<<<(E_EDGES + 255) / 256, 256, 0, stream>>>(edge_dst, cursor, sid);

    edge_kernel<<<NEDGE_BLOCKS, 256, 0, stream>>>(
        ws_h, edge_src, edge_dst, edge_attr, ES_h, W2T_g, W1T_g, BT_g,
        sid, nacc, edge_out);

    node_post_kernel<<<N_NODES / 8, 128, 0, stream>>>(
        nacc, node_attr, w_lin2_0, w_lin2_1, w_alpha, out);
}